// Round 25
// baseline (535.724 us; speedup 1.0000x reference)
//
#include <hip/hip_runtime.h>

typedef unsigned short u16;
typedef unsigned int u32;
typedef __attribute__((ext_vector_type(2))) unsigned int u32x2;
typedef __attribute__((ext_vector_type(8))) unsigned short u16x8;
typedef __attribute__((ext_vector_type(8))) __bf16 bf16x8;
typedef __attribute__((ext_vector_type(4))) float f32x4;

#define DEV __device__ __forceinline__

DEV u16 f2bf(float f) {
  unsigned u = __builtin_bit_cast(unsigned, f);
  u += 0x7FFFu + ((u >> 16) & 1u);
  return (u16)(u >> 16);
}
DEV float bf2f(u16 h) {
  unsigned u = ((unsigned)h) << 16;
  return __builtin_bit_cast(float, u);
}
DEV u32 cvtpk(float lo, float hi) {
  u32 r;
  asm("v_cvt_pk_bf16_f32 %0, %1, %2" : "=v"(r) : "v"(lo), "v"(hi));
  return r;
}
DEV float exp2r(float x) {
  float r;
  asm("v_exp_f32 %0, %1" : "=v"(r) : "v"(x));
  return r;
}
DEV float max3f(float a, float b, float c) {
  float r;
  asm("v_max3_f32 %0, %1, %2, %3" : "=v"(r) : "v"(a), "v"(b), "v"(c));
  return r;
}
DEV f32x4 mfma16(u16x8 a, u16x8 b, f32x4 c) {
  return __builtin_amdgcn_mfma_f32_16x16x32_bf16(
      __builtin_bit_cast(bf16x8, a), __builtin_bit_cast(bf16x8, b), c, 0, 0, 0);
}
DEV void gload_lds16(const void* g, void* l) {
  __builtin_amdgcn_global_load_lds(
      (const __attribute__((address_space(1))) void*)g,
      (__attribute__((address_space(3))) void*)l, 16, 0, 0);
}

DEV void cast_chunk(const float* __restrict__ src, u16* __restrict__ dst, int lc, int tid) {
  size_t i = ((size_t)lc * 2048 + tid * 8);
  float4 a = *(const float4*)(src + i);
  float4 c = *(const float4*)(src + i + 4);
  u16x8 o;
  o[0] = f2bf(a.x); o[1] = f2bf(a.y); o[2] = f2bf(a.z); o[3] = f2bf(a.w);
  o[4] = f2bf(c.x); o[5] = f2bf(c.y); o[6] = f2bf(c.z); o[7] = f2bf(c.w);
  *(u16x8*)(dst + i) = o;
}

// ---------------- fused prologue: rope table + RMSNorm(x) + QKV weight cast ----------------
__global__ __launch_bounds__(256) void prep(const float* __restrict__ x, const float* __restrict__ w_in,
                                            const float* __restrict__ wq, const float* __restrict__ wk,
                                            const float* __restrict__ wv,
                                            u16* __restrict__ HB, u16* __restrict__ outQKV,
                                            float2* __restrict__ RT) {
  const int b = blockIdx.x, tid = threadIdx.x;
  __shared__ float part[4];
  if (b < 256) {
    int idx = b * 256 + tid;  // 65536 = S*32
    int pos = idx >> 5, i = idx & 31;
    float inv = __expf(-(float)(2 * i) * (9.210340371976184f / 64.0f));
    float a = (float)pos * inv;
    float s, c;
    __sincosf(a, &s, &c);
    RT[idx] = make_float2(c, s);
  } else if (b < 2304) {
    const int row = b - 256;
    const float* xr = x + (size_t)row * 2048;
    float4 a = *(const float4*)(xr + tid * 8);
    float4 bb = *(const float4*)(xr + tid * 8 + 4);
    float ss = a.x * a.x + a.y * a.y + a.z * a.z + a.w * a.w +
               bb.x * bb.x + bb.y * bb.y + bb.z * bb.z + bb.w * bb.w;
#pragma unroll
    for (int off = 32; off; off >>= 1) ss += __shfl_xor(ss, off);
    if ((tid & 63) == 0) part[tid >> 6] = ss;
    __syncthreads();
    float tot = part[0] + part[1] + part[2] + part[3];
    float r = rsqrtf(tot * (1.0f / 2048.0f) + 1e-5f);
    float4 wa = *(const float4*)(w_in + tid * 8);
    float4 wb = *(const float4*)(w_in + tid * 8 + 4);
    u16x8 o;
    o[0] = f2bf(a.x * r * wa.x); o[1] = f2bf(a.y * r * wa.y);
    o[2] = f2bf(a.z * r * wa.z); o[3] = f2bf(a.w * r * wa.w);
    o[4] = f2bf(bb.x * r * wb.x); o[5] = f2bf(bb.y * r * wb.y);
    o[6] = f2bf(bb.z * r * wb.z); o[7] = f2bf(bb.w * r * wb.w);
    *(u16x8*)(HB + (size_t)row * 2048 + tid * 8) = o;
  } else {
    const int bb = b - 2304;  // 0..6143
    const float* src = (bb < 2048) ? wq : (bb < 4096) ? wk : wv;
    cast_chunk(src, outQKV + (size_t)(bb >> 11) * 4194304, bb & 2047, tid);
  }
}

// ---------------- RMSNorm (fp32 in) -> bf16 out (non-splitO fallback) ----------------
__global__ __launch_bounds__(256) void rmsnorm_cast(const float* __restrict__ x, const float* __restrict__ w,
                                                    u16* __restrict__ out) {
  const int row = blockIdx.x, tid = threadIdx.x;
  const float* xr = x + (size_t)row * 2048;
  float4 a = *(const float4*)(xr + tid * 8);
  float4 b = *(const float4*)(xr + tid * 8 + 4);
  float ss = a.x * a.x + a.y * a.y + a.z * a.z + a.w * a.w +
             b.x * b.x + b.y * b.y + b.z * b.z + b.w * b.w;
#pragma unroll
  for (int off = 32; off; off >>= 1) ss += __shfl_xor(ss, off);
  __shared__ float part[4];
  if ((tid & 63) == 0) part[tid >> 6] = ss;
  __syncthreads();
  float tot = part[0] + part[1] + part[2] + part[3];
  float r = rsqrtf(tot * (1.0f / 2048.0f) + 1e-5f);
  float4 wa = *(const float4*)(w + tid * 8);
  float4 wb = *(const float4*)(w + tid * 8 + 4);
  u16x8 o;
  o[0] = f2bf(a.x * r * wa.x); o[1] = f2bf(a.y * r * wa.y);
  o[2] = f2bf(a.z * r * wa.z); o[3] = f2bf(a.w * r * wa.w);
  o[4] = f2bf(b.x * r * wb.x); o[5] = f2bf(b.y * r * wb.y);
  o[6] = f2bf(b.z * r * wb.z); o[7] = f2bf(b.w * r * wb.w);
  *(u16x8*)(out + (size_t)row * 2048 + tid * 8) = o;
}

// ---------------- fused split-K reduce (bf16 partials) + residual + RMSNorm ----------------
__global__ __launch_bounds__(256) void reduce_norm(const u16* __restrict__ p, const float* __restrict__ res,
                                                   const float* __restrict__ w, float* __restrict__ x1,
                                                   u16* __restrict__ hb) {
  const int row = blockIdx.x, tid = threadIdx.x;
  const size_t n = (size_t)2048 * 2048;
  const size_t i = (size_t)row * 2048 + tid * 8;
  float v[8];
  {
    float4 r0 = *(const float4*)(res + i);
    float4 r1 = *(const float4*)(res + i + 4);
    v[0] = r0.x; v[1] = r0.y; v[2] = r0.z; v[3] = r0.w;
    v[4] = r1.x; v[5] = r1.y; v[6] = r1.z; v[7] = r1.w;
  }
#pragma unroll
  for (int s = 0; s < 4; ++s) {
    u16x8 pv = *(const u16x8*)(p + (size_t)s * n + i);
#pragma unroll
    for (int e = 0; e < 8; ++e) v[e] += bf2f(pv[e]);
  }
  *(float4*)(x1 + i) = make_float4(v[0], v[1], v[2], v[3]);
  *(float4*)(x1 + i + 4) = make_float4(v[4], v[5], v[6], v[7]);
  float ss = 0.f;
#pragma unroll
  for (int e = 0; e < 8; ++e) ss += v[e] * v[e];
#pragma unroll
  for (int off = 32; off; off >>= 1) ss += __shfl_xor(ss, off);
  __shared__ float part[4];
  if ((tid & 63) == 0) part[tid >> 6] = ss;
  __syncthreads();
  float tot = part[0] + part[1] + part[2] + part[3];
  float r = rsqrtf(tot * (1.0f / 2048.0f) + 1e-5f);
  float4 wa = *(const float4*)(w + tid * 8);
  float4 wb = *(const float4*)(w + tid * 8 + 4);
  u16x8 o;
  o[0] = f2bf(v[0] * r * wa.x); o[1] = f2bf(v[1] * r * wa.y);
  o[2] = f2bf(v[2] * r * wa.z); o[3] = f2bf(v[3] * r * wa.w);
  o[4] = f2bf(v[4] * r * wb.x); o[5] = f2bf(v[5] * r * wb.y);
  o[6] = f2bf(v[6] * r * wb.z); o[7] = f2bf(v[7] * r * wb.w);
  *(u16x8*)(hb + i) = o;
}

// ============ 256x256-tile, 8-wave, 8-phase NT GEMM, BK=64 (round-17 schedule) ============
// EPI 0: bf16 out. 1: fp32 = acc+extra(fp32). 2: bf16 = extra*silu(acc). 3: BF16 partial at z.
template <int EPI>
__global__ __launch_bounds__(512) void gemm8(const u16* __restrict__ Ag, const u16* __restrict__ Bg,
                                             void* __restrict__ outp, const void* __restrict__ extra,
                                             int M, int N, int KC, int lda, int ldb, int koffStride,
                                             long long bStrideB, long long bStrideO) {
  __shared__ u16 lds[65536];  // 128 KiB: A0 @0, B0 @16384, A1 @32768, B1 @49152 (u16)
  const int z = blockIdx.z;
  const u16* Ap = Ag;
  const u16* Bp = Bg + (EPI == 0 ? (size_t)z * bStrideB : (size_t)0);
  const int koff = (EPI == 3) ? z * koffStride : 0;
  const int nbx = N >> 8;
  const int cpx = nbx >> 3;
  const int gid = blockIdx.x;
  const int bx = (gid & 7) * cpx + ((gid >> 3) % cpx);
  const int by = (gid >> 3) / cpx;
  const int bm = by << 8, bn = bx << 8;
  const int tid = threadIdx.x;
  const int w = tid >> 6, l = tid & 63;
  const int wr = w >> 2, wc = w & 3;
  const int l16 = l & 15, l4 = l >> 4;
  const int NTT = KC >> 6, NT2 = KC >> 7;
  const int srow = l >> 3;
  const int scolB = (((l & 7) ^ srow) << 4);

  auto STG = [&](int halfU16, const u16* src, int ldx, int rowBase, int kt) {
#pragma unroll
    for (int i = 0; i < 2; ++i) {
      const int r = i * 64 + w * 8 + srow;
      const char* g = (const char*)(src + (size_t)(rowBase + r) * ldx + kt) + scolB;
      gload_lds16(g, (char*)lds + halfU16 * 2 + (i * 512 + w * 64) * 16);
    }
  };

  f32x4 acc[8][4] = {};
  u16x8 a[4][2], b[4][2];

  auto LDA8 = [&](int bufU16, int mh) {
#pragma unroll
    for (int j = 0; j < 4; ++j) {
      const int row = wr * 128 + mh * 64 + j * 16 + l16;
#pragma unroll
      for (int kk = 0; kk < 2; ++kk)
        a[j][kk] = *(const u16x8*)&lds[bufU16 + row * 64 + (((kk * 4 + l4) ^ (row & 7)) << 3)];
    }
  };
  auto LDB4 = [&](int bufU16, int nh) {
#pragma unroll
    for (int j = 0; j < 2; ++j) {
      const int nf = nh * 2 + j;
      const int row = wc * 64 + nf * 16 + l16;
#pragma unroll
      for (int kk = 0; kk < 2; ++kk)
        b[nf][kk] = *(const u16x8*)&lds[bufU16 + row * 64 + (((kk * 4 + l4) ^ (row & 7)) << 3)];
    }
  };
  auto MM = [&](int mh, int nh) {
    __builtin_amdgcn_s_setprio(1);
#pragma unroll
    for (int kk = 0; kk < 2; ++kk)
#pragma unroll
      for (int mt = 0; mt < 4; ++mt)
#pragma unroll
        for (int j = 0; j < 2; ++j)
          acc[mh * 4 + mt][nh * 2 + j] = mfma16(a[mt][kk], b[nh * 2 + j][kk], acc[mh * 4 + mt][nh * 2 + j]);
    __builtin_amdgcn_s_setprio(0);
  };

  STG(16384, Bp, ldb, bn, koff);
  STG(24576, Bp, ldb, bn + 128, koff);
  STG(0, Ap, lda, bm, koff);
  STG(8192, Ap, lda, bm + 128, koff);
  STG(49152, Bp, ldb, bn, koff + 64);
  STG(57344, Bp, ldb, bn + 128, koff + 64);
  asm volatile("s_waitcnt vmcnt(4)" ::: "memory");
  __builtin_amdgcn_sched_barrier(0);
  __builtin_amdgcn_s_barrier();

  for (int it = 0; it < NT2; ++it) {
    const int t2 = 2 * it + 2, t3 = 2 * it + 3;
    const int k1 = koff + (2 * it + 1) * 64;
    const int k2 = koff + (t2 < NTT ? t2 * 64 : 0);
    const int k3 = koff + (t3 < NTT ? t3 * 64 : 0);
    // ph1
    LDA8(0, 0); LDB4(16384, 0);
    STG(32768, Ap, lda, bm, k1);
    __builtin_amdgcn_s_barrier();
    MM(0, 0);
    __builtin_amdgcn_s_barrier();
    // ph2
    LDB4(16384, 1);
    STG(40960, Ap, lda, bm + 128, k1);
    __builtin_amdgcn_s_barrier();
    MM(0, 1);
    __builtin_amdgcn_s_barrier();
    // ph3
    LDA8(0, 1);
    STG(16384, Bp, ldb, bn, k2);
    __builtin_amdgcn_s_barrier();
    MM(1, 0);
    __builtin_amdgcn_s_barrier();
    // ph4
    STG(24576, Bp, ldb, bn + 128, k2);
    asm volatile("s_waitcnt vmcnt(4)" ::: "memory");
    __builtin_amdgcn_sched_barrier(0);
    __builtin_amdgcn_s_barrier();
    MM(1, 1);
    __builtin_amdgcn_s_barrier();
    // ph5
    LDA8(32768, 0); LDB4(49152, 0);
    STG(0, Ap, lda, bm, k2);
    __builtin_amdgcn_s_barrier();
    MM(0, 0);
    __builtin_amdgcn_s_barrier();
    // ph6
    LDB4(49152, 1);
    STG(8192, Ap, lda, bm + 128, k2);
    __builtin_amdgcn_s_barrier();
    MM(0, 1);
    __builtin_amdgcn_s_barrier();
    // ph7
    LDA8(32768, 1);
    STG(49152, Bp, ldb, bn, k3);
    __builtin_amdgcn_s_barrier();
    MM(1, 0);
    __builtin_amdgcn_s_barrier();
    // ph8
    STG(57344, Bp, ldb, bn + 128, k3);
    asm volatile("s_waitcnt vmcnt(4)" ::: "memory");
    __builtin_amdgcn_sched_barrier(0);
    __builtin_amdgcn_s_barrier();
    MM(1, 1);
    __builtin_amdgcn_s_barrier();
  }

#pragma unroll
  for (int i = 0; i < 8; ++i)
#pragma unroll
    for (int j = 0; j < 4; ++j)
#pragma unroll
      for (int r = 0; r < 4; ++r) {
        const int row = bm + wr * 128 + i * 16 + l4 * 4 + r;
        const int col = bn + wc * 64 + j * 16 + l16;
        const size_t idx = (size_t)row * N + col;
        float v = acc[i][j][r];
        if (EPI == 0) {
          ((u16*)outp)[(size_t)z * bStrideO + idx] = f2bf(v);
        } else if (EPI == 1) {
          ((float*)outp)[idx] = v + ((const float*)extra)[idx];
        } else if (EPI == 2) {
          float g = bf2f(((const u16*)extra)[idx]);
          float sig = 1.0f / (1.0f + __expf(-v));
          ((u16*)outp)[idx] = f2bf(g * v * sig);
        } else {
          ((u16*)outp)[(size_t)z * M * N + idx] = f2bf(v);  // bf16 partial
        }
      }
}

// ============ fused gate+up SwiGLU GEMM: prod = (A@Wg^T) * silu(A@Wu^T) ============
// Runs the proven round-17 K-pipeline twice (Wg -> accG, Wu -> accU); epilogue in registers.
__global__ __launch_bounds__(512) void gemm_swiglu(const u16* __restrict__ Ag, const u16* __restrict__ Bg_g,
                                                   const u16* __restrict__ Bg_u, u16* __restrict__ outp,
                                                   int M, int N, int KC, int lda, int ldb) {
  __shared__ u16 lds[65536];
  const int nbx = N >> 8;
  const int cpx = nbx >> 3;
  const int gid = blockIdx.x;
  const int bx = (gid & 7) * cpx + ((gid >> 3) % cpx);
  const int by = (gid >> 3) / cpx;
  const int bm = by << 8, bn = bx << 8;
  const int tid = threadIdx.x;
  const int w = tid >> 6, l = tid & 63;
  const int wr = w >> 2, wc = w & 3;
  const int l16 = l & 15, l4 = l >> 4;
  const int NTT = KC >> 6, NT2 = KC >> 7;
  const int srow = l >> 3;
  const int scolB = (((l & 7) ^ srow) << 4);

  f32x4 accG[8][4] = {};
  f32x4 accU[8][4] = {};
  u16x8 a[4][2], b[4][2];

  auto STG = [&](int halfU16, const u16* src, int ldx, int rowBase, int kt) {
#pragma unroll
    for (int i = 0; i < 2; ++i) {
      const int r = i * 64 + w * 8 + srow;
      const char* g = (const char*)(src + (size_t)(rowBase + r) * ldx + kt) + scolB;
      gload_lds16(g, (char*)lds + halfU16 * 2 + (i * 512 + w * 64) * 16);
    }
  };
  auto LDA8 = [&](int bufU16, int mh) {
#pragma unroll
    for (int j = 0; j < 4; ++j) {
      const int row = wr * 128 + mh * 64 + j * 16 + l16;
#pragma unroll
      for (int kk = 0; kk < 2; ++kk)
        a[j][kk] = *(const u16x8*)&lds[bufU16 + row * 64 + (((kk * 4 + l4) ^ (row & 7)) << 3)];
    }
  };
  auto LDB4 = [&](int bufU16, int nh) {
#pragma unroll
    for (int j = 0; j < 2; ++j) {
      const int nf = nh * 2 + j;
      const int row = wc * 64 + nf * 16 + l16;
#pragma unroll
      for (int kk = 0; kk < 2; ++kk)
        b[nf][kk] = *(const u16x8*)&lds[bufU16 + row * 64 + (((kk * 4 + l4) ^ (row & 7)) << 3)];
    }
  };

  auto KLOOP = [&](f32x4 (&acc)[8][4], const u16* __restrict__ Bp) {
    auto MM = [&](int mh, int nh) {
      __builtin_amdgcn_s_setprio(1);
#pragma unroll
      for (int kk = 0; kk < 2; ++kk)
#pragma unroll
        for (int mt = 0; mt < 4; ++mt)
#pragma unroll
          for (int j = 0; j < 2; ++j)
            acc[mh * 4 + mt][nh * 2 + j] = mfma16(a[mt][kk], b[nh * 2 + j][kk], acc[mh * 4 + mt][nh * 2 + j]);
      __builtin_amdgcn_s_setprio(0);
    };
    STG(16384, Bp, ldb, bn, 0);
    STG(24576, Bp, ldb, bn + 128, 0);
    STG(0, Ag, lda, bm, 0);
    STG(8192, Ag, lda, bm + 128, 0);
    STG(49152, Bp, ldb, bn, 64);
    STG(57344, Bp, ldb, bn + 128, 64);
    asm volatile("s_waitcnt vmcnt(4)" ::: "memory");
    __builtin_amdgcn_sched_barrier(0);
    __builtin_amdgcn_s_barrier();

    for (int it = 0; it < NT2; ++it) {
      const int t2 = 2 * it + 2, t3 = 2 * it + 3;
      const int k1 = (2 * it + 1) * 64;
      const int k2 = (t2 < NTT ? t2 * 64 : 0);
      const int k3 = (t3 < NTT ? t3 * 64 : 0);
      LDA8(0, 0); LDB4(16384, 0);
      STG(32768, Ag, lda, bm, k1);
      __builtin_amdgcn_s_barrier();
      MM(0, 0);
      __builtin_amdgcn_s_barrier();
      LDB4(16384, 1);
      STG(40960, Ag, lda, bm + 128, k1);
      __builtin_amdgcn_s_barrier();
      MM(0, 1);
      __builtin_amdgcn_s_barrier();
      LDA8(0, 1);
      STG(16384, Bp, ldb, bn, k2);
      __builtin_amdgcn_s_barrier();
      MM(1, 0);
      __builtin_amdgcn_s_barrier();
      STG(24576, Bp, ldb, bn + 128, k2);
      asm volatile("s_waitcnt vmcnt(4)" ::: "memory");
      __builtin_amdgcn_sched_barrier(0);
      __builtin_amdgcn_s_barrier();
      MM(1, 1);
      __builtin_amdgcn_s_barrier();
      LDA8(32768, 0); LDB4(49152, 0);
      STG(0, Ag, lda, bm, k2);
      __builtin_amdgcn_s_barrier();
      MM(0, 0);
      __builtin_amdgcn_s_barrier();
      LDB4(49152, 1);
      STG(8192, Ag, lda, bm + 128, k2);
      __builtin_amdgcn_s_barrier();
      MM(0, 1);
      __builtin_amdgcn_s_barrier();
      LDA8(32768, 1);
      STG(49152, Bp, ldb, bn, k3);
      __builtin_amdgcn_s_barrier();
      MM(1, 0);
      __builtin_amdgcn_s_barrier();
      STG(57344, Bp, ldb, bn + 128, k3);
      asm volatile("s_waitcnt vmcnt(4)" ::: "memory");
      __builtin_amdgcn_sched_barrier(0);
      __builtin_amdgcn_s_barrier();
      MM(1, 1);
      __builtin_amdgcn_s_barrier();
    }
    __builtin_amdgcn_s_barrier();  // all LDS reads done before next KLOOP restages
  };

  KLOOP(accG, Bg_g);
  KLOOP(accU, Bg_u);

#pragma unroll
  for (int i = 0; i < 8; ++i)
#pragma unroll
    for (int j = 0; j < 4; ++j)
#pragma unroll
      for (int r = 0; r < 4; ++r) {
        const int row = bm + wr * 128 + i * 16 + l4 * 4 + r;
        const int col = bn + wc * 64 + j * 16 + l16;
        const size_t idx = (size_t)row * N + col;
        float gv = accG[i][j][r];
        float uv = accU[i][j][r];
        float sig = 1.0f / (1.0f + __expf(-uv));
        outp[idx] = f2bf(gv * uv * sig);
      }
}

// ---------------- split-K reduce (bf16 partials): out = sum4(p) + res ----------------
__global__ __launch_bounds__(256) void reduce4(const u16* __restrict__ p, const float* __restrict__ res,
                                               float* __restrict__ out, size_t n) {
  size_t i = ((size_t)blockIdx.x * 256 + threadIdx.x) * 8;
  float v[8];
  {
    float4 r0 = *(const float4*)(res + i);
    float4 r1 = *(const float4*)(res + i + 4);
    v[0] = r0.x; v[1] = r0.y; v[2] = r0.z; v[3] = r0.w;
    v[4] = r1.x; v[5] = r1.y; v[6] = r1.z; v[7] = r1.w;
  }
#pragma unroll
  for (int s = 0; s < 4; ++s) {
    u16x8 pv = *(const u16x8*)(p + (size_t)s * n + i);
#pragma unroll
    for (int e = 0; e < 8; ++e) v[e] += bf2f(pv[e]);
  }
  *(float4*)(out + i) = make_float4(v[0], v[1], v[2], v[3]);
  *(float4*)(out + i + 4) = make_float4(v[4], v[5], v[6], v[7]);
}

// ---------------- fused RoPE (vectorized x8) + V transpose + W_O cast ----------------
__global__ __launch_bounds__(256) void rope_tr(u16* __restrict__ q, u16* __restrict__ k,
                                               const float2* __restrict__ tab,
                                               const u16* __restrict__ v, u16* __restrict__ vt,
                                               const float* __restrict__ wo, u16* __restrict__ outO) {
  __shared__ u16 t[64][72];
  const int b = blockIdx.x, tid = threadIdx.x;
  if (b < 1024) {
    int idx = b * 256 + tid;  // 262144 = S*32*4
    int i8 = idx & 3, hh = (idx >> 2) & 31, pos = idx >> 7;
    size_t base = (size_t)pos * 2048 + hh * 64 + i8 * 8;
    const float4* rt = (const float4*)(tab + ((size_t)pos << 5) + i8 * 8);
    float4 r0 = rt[0], r1 = rt[1], r2 = rt[2], r3 = rt[3];
    float cs[8][2] = {{r0.x, r0.y}, {r0.z, r0.w}, {r1.x, r1.y}, {r1.z, r1.w},
                      {r2.x, r2.y}, {r2.z, r2.w}, {r3.x, r3.y}, {r3.z, r3.w}};
    u16x8 qlo = *(u16x8*)(q + base), qhi = *(u16x8*)(q + base + 32);
    u16x8 klo = *(u16x8*)(k + base), khi = *(u16x8*)(k + base + 32);
    u16x8 oql, oqh, okl, okh;
#pragma unroll
    for (int e = 0; e < 8; ++e) {
      float c = cs[e][0], s = cs[e][1];
      float a0 = bf2f(qlo[e]), a1 = bf2f(qhi[e]);
      oql[e] = f2bf(a0 * c - a1 * s);
      oqh[e] = f2bf(a1 * c + a0 * s);
      float b0 = bf2f(klo[e]), b1 = bf2f(khi[e]);
      okl[e] = f2bf(b0 * c - b1 * s);
      okh[e] = f2bf(b1 * c + b0 * s);
    }
    *(u16x8*)(q + base) = oql;
    *(u16x8*)(q + base + 32) = oqh;
    *(u16x8*)(k + base) = okl;
    *(u16x8*)(k + base + 32) = okh;
  } else if (b < 2048) {
    const int bb = b - 1024;
    const int t0 = (bb & 31) * 64, h = bb >> 5;
    {
      const int r = tid >> 3, c8 = (tid & 7) * 8;
#pragma unroll
      for (int j = 0; j < 2; ++j) {
        u16x8 val = *(const u16x8*)(v + (size_t)(t0 + r + 32 * j) * 2048 + h * 64 + c8);
        *(u16x8*)&t[r + 32 * j][c8] = val;
      }
    }
    __syncthreads();
    const int d = tid >> 2, qq = (tid & 3) * 16;
    u16x8 lo, hi;
#pragma unroll
    for (int e = 0; e < 8; ++e) lo[e] = t[qq + e][d];
#pragma unroll
    for (int e = 0; e < 8; ++e) hi[e] = t[qq + 8 + e][d];
    *(u16x8*)(vt + (size_t)(h * 64 + d) * 2048 + t0 + qq) = lo;
    *(u16x8*)(vt + (size_t)(h * 64 + d) * 2048 + t0 + qq + 8) = hi;
  } else {
    cast_chunk(wo, outO, b - 2048, tid);
  }
}

// ---------------- Flash attention v8 (double-buffered KV) + G/U/D cast ----------------
__global__ __launch_bounds__(256) void attn_cast(const u16* __restrict__ qb, const u16* __restrict__ kb,
                                                 const u16* __restrict__ vt, u16* __restrict__ ob,
                                                 const float* __restrict__ wg, const float* __restrict__ wu,
                                                 const float* __restrict__ wd, u16* __restrict__ outG,
                                                 u16* __restrict__ outU, u16* __restrict__ outD) {
  __shared__ u16 KV[2][2][64 * 64];  // [buf][K|V][row][64], XOR-swizzled chunks
  __shared__ u32 P32[4][32 * 36];
  if (blockIdx.x >= 512) {
    const int cb = blockIdx.x - 512;  // 0..1535
    const int tid = threadIdx.x;
    const float* src;
    u16* dst;
    if (cb < 512) { src = wg; dst = outG; }
    else if (cb < 1024) { src = wu; dst = outU; }
    else { src = wd; dst = outD; }
    const int base = (cb & 511) * 16;
#pragma unroll
    for (int itc = 0; itc < 16; ++itc) cast_chunk(src, dst, base + itc, tid);
    return;
  }
  const int id = blockIdx.x;
  const int h = ((id & 7) << 2) | ((id >> 3) & 3);
  const int q0 = (id >> 5) << 7;
  const int w = threadIdx.x >> 6, l = threadIdx.x & 63;
  const int l16 = l & 15, l4 = l >> 4;
  const float C = 0.125f * 1.4426950408889634f;
  const float THR = 11.541560327111708f;
  const int srow8 = l >> 3;
  const int schunk = (l & 7) ^ srow8;

  auto STAGE = [&](int t0, int buf) {
#pragma unroll
    for (int j = 0; j < 2; ++j) {
      const int rg = w * 16 + j * 8;
      const int row = rg + srow8;
      gload_lds16(kb + (size_t)(t0 + row) * 2048 + h * 64 + schunk * 8, &KV[buf][0][rg * 64]);
      gload_lds16(vt + (size_t)(h * 64 + row) * 2048 + t0 + schunk * 8, &KV[buf][1][rg * 64]);
    }
  };

  u16x8 qf[2][2];
#pragma unroll
  for (int rt = 0; rt < 2; ++rt)
#pragma unroll
    for (int kh = 0; kh < 2; ++kh) {
      u16x8 q = *(const u16x8*)(qb + (size_t)(q0 + w * 32 + rt * 16 + l16) * 2048 + h * 64 + kh * 32 + l4 * 8);
#pragma unroll
      for (int e = 0; e < 8; ++e) q[e] = f2bf(bf2f(q[e]) * C);
      qf[rt][kh] = q;
    }
  float mrun[2], lrun[2];
  f32x4 oacc[2][4] = {};
#pragma unroll
  for (int i = 0; i < 2; ++i) { mrun[i] = -1e30f; lrun[i] = 0.f; }

  auto TILE = [&](int t0, int buf) {
    f32x4 sacc[2][4] = {};
#pragma unroll
    for (int kh = 0; kh < 2; ++kh)
#pragma unroll
      for (int tt = 0; tt < 4; ++tt) {
        const int row = tt * 16 + l16;
        const int ch = (kh * 4 + l4) ^ (row & 7);
        u16x8 kf = *(const u16x8*)&KV[buf][0][row * 64 + ch * 8];
#pragma unroll
        for (int rt = 0; rt < 2; ++rt)
          sacc[rt][tt] = mfma16(kf, qf[rt][kh], sacc[rt][tt]);
      }
    float pmax[2];
    int ok = 1;
#pragma unroll
    for (int rt = 0; rt < 2; ++rt) {
      float m0 = max3f(sacc[rt][0][0], sacc[rt][0][1], sacc[rt][0][2]);
      float m1 = max3f(sacc[rt][0][3], sacc[rt][1][0], sacc[rt][1][1]);
      float m2 = max3f(sacc[rt][1][2], sacc[rt][1][3], sacc[rt][2][0]);
      float m3 = max3f(sacc[rt][2][1], sacc[rt][2][2], sacc[rt][2][3]);
      float m4 = max3f(sacc[rt][3][0], sacc[rt][3][1], sacc[rt][3][2]);
      pmax[rt] = fmaxf(max3f(m0, m1, m2), max3f(m3, m4, sacc[rt][3][3]));
      ok &= (pmax[rt] <= mrun[rt] + THR) ? 1 : 0;
    }
    if (!__all(ok)) {
      float sfac[2];
#pragma unroll
      for (int rt = 0; rt < 2; ++rt) {
        float mx = pmax[rt];
        mx = fmaxf(mx, __shfl_xor(mx, 16));
        mx = fmaxf(mx, __shfl_xor(mx, 32));
        float mnew = fmaxf(mrun[rt], mx);
        sfac[rt] = exp2f(mrun[rt] - mnew);
        mrun[rt] = mnew;
        lrun[rt] *= sfac[rt];
      }
#pragma unroll
      for (int rt = 0; rt < 2; ++rt) {
        float sfo[4];
#pragma unroll
        for (int r = 0; r < 4; ++r) sfo[r] = __shfl(sfac[rt], (l & 48) + l4 * 4 + r);
#pragma unroll
        for (int nt = 0; nt < 4; ++nt)
#pragma unroll
          for (int r = 0; r < 4; ++r) oacc[rt][nt][r] *= sfo[r];
      }
    }
#pragma unroll
    for (int rt = 0; rt < 2; ++rt) {
      const int rowOff = (rt * 16 + l16) * 36 + l4 * 2;
#pragma unroll
      for (int tt = 0; tt < 4; ++tt) {
        float p0 = exp2r(sacc[rt][tt][0] - mrun[rt]);
        float p1 = exp2r(sacc[rt][tt][1] - mrun[rt]);
        float p2 = exp2r(sacc[rt][tt][2] - mrun[rt]);
        float p3 = exp2r(sacc[rt][tt][3] - mrun[rt]);
        lrun[rt] += (p0 + p1) + (p2 + p3);
        u32x2 pk;
        pk.x = cvtpk(p0, p1);
        pk.y = cvtpk(p2, p3);
        *(u32x2*)&P32[w][rowOff + tt * 8] = pk;
      }
    }
#pragma unroll
    for (int ks = 0; ks < 2; ++ks) {
      u16x8 pf[2];
#pragma unroll
      for (int rt = 0; rt < 2; ++rt)
        pf[rt] = *(const u16x8*)&P32[w][(rt * 16 + l16) * 36 + ks * 16 + l4 * 4];
#pragma unroll
      for (int nt = 0; nt < 4; ++nt) {
        const int row = nt * 16 + l16;
        const int ch = (ks * 4 + l4) ^ (row & 7);
        u16x8 vf = *(const u16x8*)&KV[buf][1][row * 64 + ch * 8];
#pragma unroll
        for (int rt = 0; rt < 2; ++rt)
          oacc[rt][nt] = mfma16(pf[rt], vf, oacc[rt][nt]);
      }
    }
  };

  STAGE(0, 0);
  __syncthreads();
  for (int t = 0; t < 32; t += 2) {
    STAGE((t + 1) * 64, 1);
    TILE(t * 64, 0);
    __syncthreads();
    if (t < 30) STAGE((t + 2) * 64, 0);
    TILE((t + 1) * 64, 1);
    __syncthreads();
  }
#pragma unroll
  for (int rt = 0; rt < 2; ++rt) {
    lrun[rt] += __shfl_xor(lrun[rt], 16);
    lrun[rt] += __shfl_xor(lrun[rt], 32);
  }
#pragma unroll
  for (int rt = 0; rt < 2; ++rt) {
    float linv[4];
#pragma unroll
    for (int r = 0; r < 4; ++r) linv[r] = 1.0f / __shfl(lrun[rt], (l & 48) + l4 * 4 + r);
#pragma unroll
    for (int r = 0; r < 4; ++r)
#pragma unroll
      for (int nt = 0; nt < 4; ++nt)
        ob[(size_t)(q0 + w * 32 + rt * 16 + l4 * 4 + r) * 2048 + h * 64 + nt * 16 + l16] =
            f2bf(oacc[rt][nt][r] * linv[r]);
  }
}

extern "C" void kernel_launch(void* const* d_in, const int* in_sizes, int n_in,
                              void* d_out, int out_size, void* d_ws, size_t ws_size,
                              hipStream_t stream) {
  const float* x    = (const float*)d_in[0];
  const float* w_in = (const float*)d_in[1];
  const float* wq   = (const float*)d_in[2];
  const float* wk   = (const float*)d_in[3];
  const float* wv   = (const float*)d_in[4];
  const float* wo   = (const float*)d_in[5];
  const float* w_pn = (const float*)d_in[6];
  const float* wg   = (const float*)d_in[7];
  const float* wu   = (const float*)d_in[8];
  const float* wd   = (const float*)d_in[9];
  float* out = (float*)d_out;
  char* ws = (char*)d_ws;
  const size_t MB = 1ull << 20;
  const int S = 2048, D = 2048, FF = 8192;

  u16* W_QKV = (u16*)(ws);               // 24 MB
  u16* W_O   = (u16*)(ws + 24 * MB);     // 8 MB
  u16* W_G   = (u16*)(ws + 32 * MB);     // 32 MB
  u16* W_U   = (u16*)(ws + 64 * MB);     // 32 MB
  u16* W_D   = (u16*)(ws + 96 * MB);     // 32 MB
  u16* HB    = (u16*)(ws + 128 * MB);    // 8 MB
  u16* QKVB  = (u16*)(ws + 136 * MB);    // 24 MB (q,k,v)
  u16* VT    = (u16*)(ws + 160 * MB);    // 8 MB
  u16* ATTNB = (u16*)(ws + 168 * MB);    // 8 MB
  float* X1  = (float*)(ws + 176 * MB);  // 16 MB
  u16* H2B   = (u16*)(ws + 192 * MB);    // 8 MB
  float2* RT = (float2*)(ws + 200 * MB); // 0.5 MB
  u16* PRODB = (u16*)(ws + 136 * MB);    // 32 MB, overlays QKVB+VT (dead after attention)
  u16* DP    = (u16*)(ws);               // 32 MB bf16 down-proj partials (overlays W_QKV+W_O, dead)
  u16* OP    = (u16*)(ws + 208 * MB);    // 32 MB bf16 O-proj partials
  const bool splitO = ws_size >= 240 * MB;

  prep<<<8448, 256, 0, stream>>>(x, w_in, wq, wk, wv, HB, W_QKV, RT);
  gemm8<0><<<dim3(64, 1, 3), 512, 0, stream>>>(HB, W_QKV, QKVB, nullptr, S, D, D, D, D, 0,
                                               (long long)D * D, (long long)S * D);
  rope_tr<<<4096, 256, 0, stream>>>(QKVB, QKVB + (size_t)S * D, RT, QKVB + 2 * (size_t)S * D, VT, wo, W_O);
  attn_cast<<<2048, 256, 0, stream>>>(QKVB, QKVB + (size_t)S * D, VT, ATTNB, wg, wu, wd, W_G, W_U, W_D);
  if (splitO) {
    gemm8<3><<<dim3(64, 1, 4), 512, 0, stream>>>(ATTNB, W_O, OP, nullptr, S, D, 512, D, D, 512, 0, 0);
    reduce_norm<<<S, 256, 0, stream>>>(OP, x, w_pn, X1, H2B);
  } else {
    gemm8<1><<<dim3(64, 1, 1), 512, 0, stream>>>(ATTNB, W_O, X1, x, S, D, D, D, D, 0, 0, 0);
    rmsnorm_cast<<<S, 256, 0, stream>>>(X1, w_pn, H2B);
  }
  gemm_swiglu<<<dim3(256, 1, 1), 512, 0, stream>>>(H2B, W_G, W_U, PRODB, S, FF, D, D, D);
  gemm8<3><<<dim3(64, 1, 4), 512, 0, stream>>>(PRODB, W_D, DP, nullptr, S, D, 2048, FF, FF, 2048, 0, 0);
  reduce4<<<(S * D) / 2048, 256, 0, stream>>>(DP, X1, out, (size_t)S * D);
  (void)in_sizes; (void)n_in; (void)out_size;
}

// Round 26
// 428.129 us; speedup vs baseline: 1.2513x; 1.2513x over previous
//
#include <hip/hip_runtime.h>

typedef unsigned short u16;
typedef unsigned int u32;
typedef __attribute__((ext_vector_type(2))) unsigned int u32x2;
typedef __attribute__((ext_vector_type(8))) unsigned short u16x8;
typedef __attribute__((ext_vector_type(8))) __bf16 bf16x8;
typedef __attribute__((ext_vector_type(4))) float f32x4;

#define DEV __device__ __forceinline__

DEV u16 f2bf(float f) {
  unsigned u = __builtin_bit_cast(unsigned, f);
  u += 0x7FFFu + ((u >> 16) & 1u);
  return (u16)(u >> 16);
}
DEV float bf2f(u16 h) {
  unsigned u = ((unsigned)h) << 16;
  return __builtin_bit_cast(float, u);
}
DEV u32 cvtpk(float lo, float hi) {
  u32 r;
  asm("v_cvt_pk_bf16_f32 %0, %1, %2" : "=v"(r) : "v"(lo), "v"(hi));
  return r;
}
DEV float exp2r(float x) {
  float r;
  asm("v_exp_f32 %0, %1" : "=v"(r) : "v"(x));
  return r;
}
DEV float max3f(float a, float b, float c) {
  float r;
  asm("v_max3_f32 %0, %1, %2, %3" : "=v"(r) : "v"(a), "v"(b), "v"(c));
  return r;
}
DEV f32x4 mfma16(u16x8 a, u16x8 b, f32x4 c) {
  return __builtin_amdgcn_mfma_f32_16x16x32_bf16(
      __builtin_bit_cast(bf16x8, a), __builtin_bit_cast(bf16x8, b), c, 0, 0, 0);
}
DEV void gload_lds16(const void* g, void* l) {
  __builtin_amdgcn_global_load_lds(
      (const __attribute__((address_space(1))) void*)g,
      (__attribute__((address_space(3))) void*)l, 16, 0, 0);
}

DEV void cast_chunk(const float* __restrict__ src, u16* __restrict__ dst, int lc, int tid) {
  size_t i = ((size_t)lc * 2048 + tid * 8);
  float4 a = *(const float4*)(src + i);
  float4 c = *(const float4*)(src + i + 4);
  u16x8 o;
  o[0] = f2bf(a.x); o[1] = f2bf(a.y); o[2] = f2bf(a.z); o[3] = f2bf(a.w);
  o[4] = f2bf(c.x); o[5] = f2bf(c.y); o[6] = f2bf(c.z); o[7] = f2bf(c.w);
  *(u16x8*)(dst + i) = o;
}

// ---------------- fused prologue: rope table + RMSNorm(x) + QKV weight cast ----------------
__global__ __launch_bounds__(256) void prep(const float* __restrict__ x, const float* __restrict__ w_in,
                                            const float* __restrict__ wq, const float* __restrict__ wk,
                                            const float* __restrict__ wv,
                                            u16* __restrict__ HB, u16* __restrict__ outQKV,
                                            float2* __restrict__ RT) {
  const int b = blockIdx.x, tid = threadIdx.x;
  __shared__ float part[4];
  if (b < 256) {
    int idx = b * 256 + tid;  // 65536 = S*32
    int pos = idx >> 5, i = idx & 31;
    float inv = __expf(-(float)(2 * i) * (9.210340371976184f / 64.0f));
    float a = (float)pos * inv;
    float s, c;
    __sincosf(a, &s, &c);
    RT[idx] = make_float2(c, s);
  } else if (b < 2304) {
    const int row = b - 256;
    const float* xr = x + (size_t)row * 2048;
    float4 a = *(const float4*)(xr + tid * 8);
    float4 bb = *(const float4*)(xr + tid * 8 + 4);
    float ss = a.x * a.x + a.y * a.y + a.z * a.z + a.w * a.w +
               bb.x * bb.x + bb.y * bb.y + bb.z * bb.z + bb.w * bb.w;
#pragma unroll
    for (int off = 32; off; off >>= 1) ss += __shfl_xor(ss, off);
    if ((tid & 63) == 0) part[tid >> 6] = ss;
    __syncthreads();
    float tot = part[0] + part[1] + part[2] + part[3];
    float r = rsqrtf(tot * (1.0f / 2048.0f) + 1e-5f);
    float4 wa = *(const float4*)(w_in + tid * 8);
    float4 wb = *(const float4*)(w_in + tid * 8 + 4);
    u16x8 o;
    o[0] = f2bf(a.x * r * wa.x); o[1] = f2bf(a.y * r * wa.y);
    o[2] = f2bf(a.z * r * wa.z); o[3] = f2bf(a.w * r * wa.w);
    o[4] = f2bf(bb.x * r * wb.x); o[5] = f2bf(bb.y * r * wb.y);
    o[6] = f2bf(bb.z * r * wb.z); o[7] = f2bf(bb.w * r * wb.w);
    *(u16x8*)(HB + (size_t)row * 2048 + tid * 8) = o;
  } else {
    const int bb = b - 2304;  // 0..6143
    const float* src = (bb < 2048) ? wq : (bb < 4096) ? wk : wv;
    cast_chunk(src, outQKV + (size_t)(bb >> 11) * 4194304, bb & 2047, tid);
  }
}

// ---------------- RMSNorm (fp32 in) -> bf16 out (non-splitO fallback) ----------------
__global__ __launch_bounds__(256) void rmsnorm_cast(const float* __restrict__ x, const float* __restrict__ w,
                                                    u16* __restrict__ out) {
  const int row = blockIdx.x, tid = threadIdx.x;
  const float* xr = x + (size_t)row * 2048;
  float4 a = *(const float4*)(xr + tid * 8);
  float4 b = *(const float4*)(xr + tid * 8 + 4);
  float ss = a.x * a.x + a.y * a.y + a.z * a.z + a.w * a.w +
             b.x * b.x + b.y * b.y + b.z * b.z + b.w * b.w;
#pragma unroll
  for (int off = 32; off; off >>= 1) ss += __shfl_xor(ss, off);
  __shared__ float part[4];
  if ((tid & 63) == 0) part[tid >> 6] = ss;
  __syncthreads();
  float tot = part[0] + part[1] + part[2] + part[3];
  float r = rsqrtf(tot * (1.0f / 2048.0f) + 1e-5f);
  float4 wa = *(const float4*)(w + tid * 8);
  float4 wb = *(const float4*)(w + tid * 8 + 4);
  u16x8 o;
  o[0] = f2bf(a.x * r * wa.x); o[1] = f2bf(a.y * r * wa.y);
  o[2] = f2bf(a.z * r * wa.z); o[3] = f2bf(a.w * r * wa.w);
  o[4] = f2bf(b.x * r * wb.x); o[5] = f2bf(b.y * r * wb.y);
  o[6] = f2bf(b.z * r * wb.z); o[7] = f2bf(b.w * r * wb.w);
  *(u16x8*)(out + (size_t)row * 2048 + tid * 8) = o;
}

// ---------------- fused split-K reduce (bf16 partials) + residual + RMSNorm ----------------
__global__ __launch_bounds__(256) void reduce_norm(const u16* __restrict__ p, const float* __restrict__ res,
                                                   const float* __restrict__ w, float* __restrict__ x1,
                                                   u16* __restrict__ hb) {
  const int row = blockIdx.x, tid = threadIdx.x;
  const size_t n = (size_t)2048 * 2048;
  const size_t i = (size_t)row * 2048 + tid * 8;
  float v[8];
  {
    float4 r0 = *(const float4*)(res + i);
    float4 r1 = *(const float4*)(res + i + 4);
    v[0] = r0.x; v[1] = r0.y; v[2] = r0.z; v[3] = r0.w;
    v[4] = r1.x; v[5] = r1.y; v[6] = r1.z; v[7] = r1.w;
  }
#pragma unroll
  for (int s = 0; s < 4; ++s) {
    u16x8 pv = *(const u16x8*)(p + (size_t)s * n + i);
#pragma unroll
    for (int e = 0; e < 8; ++e) v[e] += bf2f(pv[e]);
  }
  *(float4*)(x1 + i) = make_float4(v[0], v[1], v[2], v[3]);
  *(float4*)(x1 + i + 4) = make_float4(v[4], v[5], v[6], v[7]);
  float ss = 0.f;
#pragma unroll
  for (int e = 0; e < 8; ++e) ss += v[e] * v[e];
#pragma unroll
  for (int off = 32; off; off >>= 1) ss += __shfl_xor(ss, off);
  __shared__ float part[4];
  if ((tid & 63) == 0) part[tid >> 6] = ss;
  __syncthreads();
  float tot = part[0] + part[1] + part[2] + part[3];
  float r = rsqrtf(tot * (1.0f / 2048.0f) + 1e-5f);
  float4 wa = *(const float4*)(w + tid * 8);
  float4 wb = *(const float4*)(w + tid * 8 + 4);
  u16x8 o;
  o[0] = f2bf(v[0] * r * wa.x); o[1] = f2bf(v[1] * r * wa.y);
  o[2] = f2bf(v[2] * r * wa.z); o[3] = f2bf(v[3] * r * wa.w);
  o[4] = f2bf(v[4] * r * wb.x); o[5] = f2bf(v[5] * r * wb.y);
  o[6] = f2bf(v[6] * r * wb.z); o[7] = f2bf(v[7] * r * wb.w);
  *(u16x8*)(hb + i) = o;
}

// ============ 256x256-tile, 8-wave, 8-phase NT GEMM, BK=64 (round-17 schedule) ============
// EPI 0: bf16 out. 1: fp32 = acc+extra(fp32). 2: bf16 = extra*silu(acc). 3: BF16 partial at z.
template <int EPI>
__global__ __launch_bounds__(512) void gemm8(const u16* __restrict__ Ag, const u16* __restrict__ Bg,
                                             void* __restrict__ outp, const void* __restrict__ extra,
                                             int M, int N, int KC, int lda, int ldb, int koffStride,
                                             long long bStrideB, long long bStrideO) {
  __shared__ u16 lds[65536];  // 128 KiB: A0 @0, B0 @16384, A1 @32768, B1 @49152 (u16)
  const int z = blockIdx.z;
  const u16* Ap = Ag;
  const u16* Bp = Bg + (EPI == 0 ? (size_t)z * bStrideB : (size_t)0);
  const int koff = (EPI == 3) ? z * koffStride : 0;
  const int nbx = N >> 8;
  const int cpx = nbx >> 3;
  const int gid = blockIdx.x;
  const int bx = (gid & 7) * cpx + ((gid >> 3) % cpx);
  const int by = (gid >> 3) / cpx;
  const int bm = by << 8, bn = bx << 8;
  const int tid = threadIdx.x;
  const int w = tid >> 6, l = tid & 63;
  const int wr = w >> 2, wc = w & 3;
  const int l16 = l & 15, l4 = l >> 4;
  const int NTT = KC >> 6, NT2 = KC >> 7;
  const int srow = l >> 3;
  const int scolB = (((l & 7) ^ srow) << 4);

  auto STG = [&](int halfU16, const u16* src, int ldx, int rowBase, int kt) {
#pragma unroll
    for (int i = 0; i < 2; ++i) {
      const int r = i * 64 + w * 8 + srow;
      const char* g = (const char*)(src + (size_t)(rowBase + r) * ldx + kt) + scolB;
      gload_lds16(g, (char*)lds + halfU16 * 2 + (i * 512 + w * 64) * 16);
    }
  };

  f32x4 acc[8][4] = {};
  u16x8 a[4][2], b[4][2];

  auto LDA8 = [&](int bufU16, int mh) {
#pragma unroll
    for (int j = 0; j < 4; ++j) {
      const int row = wr * 128 + mh * 64 + j * 16 + l16;
#pragma unroll
      for (int kk = 0; kk < 2; ++kk)
        a[j][kk] = *(const u16x8*)&lds[bufU16 + row * 64 + (((kk * 4 + l4) ^ (row & 7)) << 3)];
    }
  };
  auto LDB4 = [&](int bufU16, int nh) {
#pragma unroll
    for (int j = 0; j < 2; ++j) {
      const int nf = nh * 2 + j;
      const int row = wc * 64 + nf * 16 + l16;
#pragma unroll
      for (int kk = 0; kk < 2; ++kk)
        b[nf][kk] = *(const u16x8*)&lds[bufU16 + row * 64 + (((kk * 4 + l4) ^ (row & 7)) << 3)];
    }
  };
  auto MM = [&](int mh, int nh) {
    __builtin_amdgcn_s_setprio(1);
#pragma unroll
    for (int kk = 0; kk < 2; ++kk)
#pragma unroll
      for (int mt = 0; mt < 4; ++mt)
#pragma unroll
        for (int j = 0; j < 2; ++j)
          acc[mh * 4 + mt][nh * 2 + j] = mfma16(a[mt][kk], b[nh * 2 + j][kk], acc[mh * 4 + mt][nh * 2 + j]);
    __builtin_amdgcn_s_setprio(0);
  };

  STG(16384, Bp, ldb, bn, koff);
  STG(24576, Bp, ldb, bn + 128, koff);
  STG(0, Ap, lda, bm, koff);
  STG(8192, Ap, lda, bm + 128, koff);
  STG(49152, Bp, ldb, bn, koff + 64);
  STG(57344, Bp, ldb, bn + 128, koff + 64);
  asm volatile("s_waitcnt vmcnt(4)" ::: "memory");
  __builtin_amdgcn_sched_barrier(0);
  __builtin_amdgcn_s_barrier();

  for (int it = 0; it < NT2; ++it) {
    const int t2 = 2 * it + 2, t3 = 2 * it + 3;
    const int k1 = koff + (2 * it + 1) * 64;
    const int k2 = koff + (t2 < NTT ? t2 * 64 : 0);
    const int k3 = koff + (t3 < NTT ? t3 * 64 : 0);
    // ph1
    LDA8(0, 0); LDB4(16384, 0);
    STG(32768, Ap, lda, bm, k1);
    __builtin_amdgcn_s_barrier();
    MM(0, 0);
    __builtin_amdgcn_s_barrier();
    // ph2
    LDB4(16384, 1);
    STG(40960, Ap, lda, bm + 128, k1);
    __builtin_amdgcn_s_barrier();
    MM(0, 1);
    __builtin_amdgcn_s_barrier();
    // ph3
    LDA8(0, 1);
    STG(16384, Bp, ldb, bn, k2);
    __builtin_amdgcn_s_barrier();
    MM(1, 0);
    __builtin_amdgcn_s_barrier();
    // ph4
    STG(24576, Bp, ldb, bn + 128, k2);
    asm volatile("s_waitcnt vmcnt(4)" ::: "memory");
    __builtin_amdgcn_sched_barrier(0);
    __builtin_amdgcn_s_barrier();
    MM(1, 1);
    __builtin_amdgcn_s_barrier();
    // ph5
    LDA8(32768, 0); LDB4(49152, 0);
    STG(0, Ap, lda, bm, k2);
    __builtin_amdgcn_s_barrier();
    MM(0, 0);
    __builtin_amdgcn_s_barrier();
    // ph6
    LDB4(49152, 1);
    STG(8192, Ap, lda, bm + 128, k2);
    __builtin_amdgcn_s_barrier();
    MM(0, 1);
    __builtin_amdgcn_s_barrier();
    // ph7
    LDA8(32768, 1);
    STG(49152, Bp, ldb, bn, k3);
    __builtin_amdgcn_s_barrier();
    MM(1, 0);
    __builtin_amdgcn_s_barrier();
    // ph8
    STG(57344, Bp, ldb, bn + 128, k3);
    asm volatile("s_waitcnt vmcnt(4)" ::: "memory");
    __builtin_amdgcn_sched_barrier(0);
    __builtin_amdgcn_s_barrier();
    MM(1, 1);
    __builtin_amdgcn_s_barrier();
  }

#pragma unroll
  for (int i = 0; i < 8; ++i)
#pragma unroll
    for (int j = 0; j < 4; ++j)
#pragma unroll
      for (int r = 0; r < 4; ++r) {
        const int row = bm + wr * 128 + i * 16 + l4 * 4 + r;
        const int col = bn + wc * 64 + j * 16 + l16;
        const size_t idx = (size_t)row * N + col;
        float v = acc[i][j][r];
        if (EPI == 0) {
          ((u16*)outp)[(size_t)z * bStrideO + idx] = f2bf(v);
        } else if (EPI == 1) {
          ((float*)outp)[idx] = v + ((const float*)extra)[idx];
        } else if (EPI == 2) {
          float g = bf2f(((const u16*)extra)[idx]);
          float sig = 1.0f / (1.0f + __expf(-v));
          ((u16*)outp)[idx] = f2bf(g * v * sig);
        } else {
          ((u16*)outp)[(size_t)z * M * N + idx] = f2bf(v);  // bf16 partial
        }
      }
}

// ---------------- split-K reduce (bf16 partials): out = sum4(p) + res ----------------
__global__ __launch_bounds__(256) void reduce4(const u16* __restrict__ p, const float* __restrict__ res,
                                               float* __restrict__ out, size_t n) {
  size_t i = ((size_t)blockIdx.x * 256 + threadIdx.x) * 8;
  float v[8];
  {
    float4 r0 = *(const float4*)(res + i);
    float4 r1 = *(const float4*)(res + i + 4);
    v[0] = r0.x; v[1] = r0.y; v[2] = r0.z; v[3] = r0.w;
    v[4] = r1.x; v[5] = r1.y; v[6] = r1.z; v[7] = r1.w;
  }
#pragma unroll
  for (int s = 0; s < 4; ++s) {
    u16x8 pv = *(const u16x8*)(p + (size_t)s * n + i);
#pragma unroll
    for (int e = 0; e < 8; ++e) v[e] += bf2f(pv[e]);
  }
  *(float4*)(out + i) = make_float4(v[0], v[1], v[2], v[3]);
  *(float4*)(out + i + 4) = make_float4(v[4], v[5], v[6], v[7]);
}

// ---------------- fused RoPE (vectorized x8) + V transpose + W_O cast ----------------
__global__ __launch_bounds__(256) void rope_tr(u16* __restrict__ q, u16* __restrict__ k,
                                               const float2* __restrict__ tab,
                                               const u16* __restrict__ v, u16* __restrict__ vt,
                                               const float* __restrict__ wo, u16* __restrict__ outO) {
  __shared__ u16 t[64][72];
  const int b = blockIdx.x, tid = threadIdx.x;
  if (b < 1024) {
    int idx = b * 256 + tid;  // 262144 = S*32*4
    int i8 = idx & 3, hh = (idx >> 2) & 31, pos = idx >> 7;
    size_t base = (size_t)pos * 2048 + hh * 64 + i8 * 8;
    const float4* rt = (const float4*)(tab + ((size_t)pos << 5) + i8 * 8);
    float4 r0 = rt[0], r1 = rt[1], r2 = rt[2], r3 = rt[3];
    float cs[8][2] = {{r0.x, r0.y}, {r0.z, r0.w}, {r1.x, r1.y}, {r1.z, r1.w},
                      {r2.x, r2.y}, {r2.z, r2.w}, {r3.x, r3.y}, {r3.z, r3.w}};
    u16x8 qlo = *(u16x8*)(q + base), qhi = *(u16x8*)(q + base + 32);
    u16x8 klo = *(u16x8*)(k + base), khi = *(u16x8*)(k + base + 32);
    u16x8 oql, oqh, okl, okh;
#pragma unroll
    for (int e = 0; e < 8; ++e) {
      float c = cs[e][0], s = cs[e][1];
      float a0 = bf2f(qlo[e]), a1 = bf2f(qhi[e]);
      oql[e] = f2bf(a0 * c - a1 * s);
      oqh[e] = f2bf(a1 * c + a0 * s);
      float b0 = bf2f(klo[e]), b1 = bf2f(khi[e]);
      okl[e] = f2bf(b0 * c - b1 * s);
      okh[e] = f2bf(b1 * c + b0 * s);
    }
    *(u16x8*)(q + base) = oql;
    *(u16x8*)(q + base + 32) = oqh;
    *(u16x8*)(k + base) = okl;
    *(u16x8*)(k + base + 32) = okh;
  } else if (b < 2048) {
    const int bb = b - 1024;
    const int t0 = (bb & 31) * 64, h = bb >> 5;
    {
      const int r = tid >> 3, c8 = (tid & 7) * 8;
#pragma unroll
      for (int j = 0; j < 2; ++j) {
        u16x8 val = *(const u16x8*)(v + (size_t)(t0 + r + 32 * j) * 2048 + h * 64 + c8);
        *(u16x8*)&t[r + 32 * j][c8] = val;
      }
    }
    __syncthreads();
    const int d = tid >> 2, qq = (tid & 3) * 16;
    u16x8 lo, hi;
#pragma unroll
    for (int e = 0; e < 8; ++e) lo[e] = t[qq + e][d];
#pragma unroll
    for (int e = 0; e < 8; ++e) hi[e] = t[qq + 8 + e][d];
    *(u16x8*)(vt + (size_t)(h * 64 + d) * 2048 + t0 + qq) = lo;
    *(u16x8*)(vt + (size_t)(h * 64 + d) * 2048 + t0 + qq + 8) = hi;
  } else {
    cast_chunk(wo, outO, b - 2048, tid);
  }
}

// ---------------- Flash attention v8 (double-buffered KV) + G/U/D cast ----------------
__global__ __launch_bounds__(256) void attn_cast(const u16* __restrict__ qb, const u16* __restrict__ kb,
                                                 const u16* __restrict__ vt, u16* __restrict__ ob,
                                                 const float* __restrict__ wg, const float* __restrict__ wu,
                                                 const float* __restrict__ wd, u16* __restrict__ outG,
                                                 u16* __restrict__ outU, u16* __restrict__ outD) {
  __shared__ u16 KV[2][2][64 * 64];  // [buf][K|V][row][64], XOR-swizzled chunks
  __shared__ u32 P32[4][32 * 36];
  if (blockIdx.x >= 512) {
    const int cb = blockIdx.x - 512;  // 0..1535
    const int tid = threadIdx.x;
    const float* src;
    u16* dst;
    if (cb < 512) { src = wg; dst = outG; }
    else if (cb < 1024) { src = wu; dst = outU; }
    else { src = wd; dst = outD; }
    const int base = (cb & 511) * 16;
#pragma unroll
    for (int itc = 0; itc < 16; ++itc) cast_chunk(src, dst, base + itc, tid);
    return;
  }
  const int id = blockIdx.x;
  const int h = ((id & 7) << 2) | ((id >> 3) & 3);
  const int q0 = (id >> 5) << 7;
  const int w = threadIdx.x >> 6, l = threadIdx.x & 63;
  const int l16 = l & 15, l4 = l >> 4;
  const float C = 0.125f * 1.4426950408889634f;
  const float THR = 11.541560327111708f;
  const int srow8 = l >> 3;
  const int schunk = (l & 7) ^ srow8;

  auto STAGE = [&](int t0, int buf) {
#pragma unroll
    for (int j = 0; j < 2; ++j) {
      const int rg = w * 16 + j * 8;
      const int row = rg + srow8;
      gload_lds16(kb + (size_t)(t0 + row) * 2048 + h * 64 + schunk * 8, &KV[buf][0][rg * 64]);
      gload_lds16(vt + (size_t)(h * 64 + row) * 2048 + t0 + schunk * 8, &KV[buf][1][rg * 64]);
    }
  };

  u16x8 qf[2][2];
#pragma unroll
  for (int rt = 0; rt < 2; ++rt)
#pragma unroll
    for (int kh = 0; kh < 2; ++kh) {
      u16x8 q = *(const u16x8*)(qb + (size_t)(q0 + w * 32 + rt * 16 + l16) * 2048 + h * 64 + kh * 32 + l4 * 8);
#pragma unroll
      for (int e = 0; e < 8; ++e) q[e] = f2bf(bf2f(q[e]) * C);
      qf[rt][kh] = q;
    }
  float mrun[2], lrun[2];
  f32x4 oacc[2][4] = {};
#pragma unroll
  for (int i = 0; i < 2; ++i) { mrun[i] = -1e30f; lrun[i] = 0.f; }

  auto TILE = [&](int t0, int buf) {
    f32x4 sacc[2][4] = {};
#pragma unroll
    for (int kh = 0; kh < 2; ++kh)
#pragma unroll
      for (int tt = 0; tt < 4; ++tt) {
        const int row = tt * 16 + l16;
        const int ch = (kh * 4 + l4) ^ (row & 7);
        u16x8 kf = *(const u16x8*)&KV[buf][0][row * 64 + ch * 8];
#pragma unroll
        for (int rt = 0; rt < 2; ++rt)
          sacc[rt][tt] = mfma16(kf, qf[rt][kh], sacc[rt][tt]);
      }
    float pmax[2];
    int ok = 1;
#pragma unroll
    for (int rt = 0; rt < 2; ++rt) {
      float m0 = max3f(sacc[rt][0][0], sacc[rt][0][1], sacc[rt][0][2]);
      float m1 = max3f(sacc[rt][0][3], sacc[rt][1][0], sacc[rt][1][1]);
      float m2 = max3f(sacc[rt][1][2], sacc[rt][1][3], sacc[rt][2][0]);
      float m3 = max3f(sacc[rt][2][1], sacc[rt][2][2], sacc[rt][2][3]);
      float m4 = max3f(sacc[rt][3][0], sacc[rt][3][1], sacc[rt][3][2]);
      pmax[rt] = fmaxf(max3f(m0, m1, m2), max3f(m3, m4, sacc[rt][3][3]));
      ok &= (pmax[rt] <= mrun[rt] + THR) ? 1 : 0;
    }
    if (!__all(ok)) {
      float sfac[2];
#pragma unroll
      for (int rt = 0; rt < 2; ++rt) {
        float mx = pmax[rt];
        mx = fmaxf(mx, __shfl_xor(mx, 16));
        mx = fmaxf(mx, __shfl_xor(mx, 32));
        float mnew = fmaxf(mrun[rt], mx);
        sfac[rt] = exp2f(mrun[rt] - mnew);
        mrun[rt] = mnew;
        lrun[rt] *= sfac[rt];
      }
#pragma unroll
      for (int rt = 0; rt < 2; ++rt) {
        float sfo[4];
#pragma unroll
        for (int r = 0; r < 4; ++r) sfo[r] = __shfl(sfac[rt], (l & 48) + l4 * 4 + r);
#pragma unroll
        for (int nt = 0; nt < 4; ++nt)
#pragma unroll
          for (int r = 0; r < 4; ++r) oacc[rt][nt][r] *= sfo[r];
      }
    }
#pragma unroll
    for (int rt = 0; rt < 2; ++rt) {
      const int rowOff = (rt * 16 + l16) * 36 + l4 * 2;
#pragma unroll
      for (int tt = 0; tt < 4; ++tt) {
        float p0 = exp2r(sacc[rt][tt][0] - mrun[rt]);
        float p1 = exp2r(sacc[rt][tt][1] - mrun[rt]);
        float p2 = exp2r(sacc[rt][tt][2] - mrun[rt]);
        float p3 = exp2r(sacc[rt][tt][3] - mrun[rt]);
        lrun[rt] += (p0 + p1) + (p2 + p3);
        u32x2 pk;
        pk.x = cvtpk(p0, p1);
        pk.y = cvtpk(p2, p3);
        *(u32x2*)&P32[w][rowOff + tt * 8] = pk;
      }
    }
#pragma unroll
    for (int ks = 0; ks < 2; ++ks) {
      u16x8 pf[2];
#pragma unroll
      for (int rt = 0; rt < 2; ++rt)
        pf[rt] = *(const u16x8*)&P32[w][(rt * 16 + l16) * 36 + ks * 16 + l4 * 4];
#pragma unroll
      for (int nt = 0; nt < 4; ++nt) {
        const int row = nt * 16 + l16;
        const int ch = (ks * 4 + l4) ^ (row & 7);
        u16x8 vf = *(const u16x8*)&KV[buf][1][row * 64 + ch * 8];
#pragma unroll
        for (int rt = 0; rt < 2; ++rt)
          oacc[rt][nt] = mfma16(pf[rt], vf, oacc[rt][nt]);
      }
    }
  };

  STAGE(0, 0);
  __syncthreads();
  for (int t = 0; t < 32; t += 2) {
    STAGE((t + 1) * 64, 1);
    TILE(t * 64, 0);
    __syncthreads();
    if (t < 30) STAGE((t + 2) * 64, 0);
    TILE((t + 1) * 64, 1);
    __syncthreads();
  }
#pragma unroll
  for (int rt = 0; rt < 2; ++rt) {
    lrun[rt] += __shfl_xor(lrun[rt], 16);
    lrun[rt] += __shfl_xor(lrun[rt], 32);
  }
#pragma unroll
  for (int rt = 0; rt < 2; ++rt) {
    float linv[4];
#pragma unroll
    for (int r = 0; r < 4; ++r) linv[r] = 1.0f / __shfl(lrun[rt], (l & 48) + l4 * 4 + r);
#pragma unroll
    for (int r = 0; r < 4; ++r)
#pragma unroll
      for (int nt = 0; nt < 4; ++nt)
        ob[(size_t)(q0 + w * 32 + rt * 16 + l4 * 4 + r) * 2048 + h * 64 + nt * 16 + l16] =
            f2bf(oacc[rt][nt][r] * linv[r]);
  }
}

extern "C" void kernel_launch(void* const* d_in, const int* in_sizes, int n_in,
                              void* d_out, int out_size, void* d_ws, size_t ws_size,
                              hipStream_t stream) {
  const float* x    = (const float*)d_in[0];
  const float* w_in = (const float*)d_in[1];
  const float* wq   = (const float*)d_in[2];
  const float* wk   = (const float*)d_in[3];
  const float* wv   = (const float*)d_in[4];
  const float* wo   = (const float*)d_in[5];
  const float* w_pn = (const float*)d_in[6];
  const float* wg   = (const float*)d_in[7];
  const float* wu   = (const float*)d_in[8];
  const float* wd   = (const float*)d_in[9];
  float* out = (float*)d_out;
  char* ws = (char*)d_ws;
  const size_t MB = 1ull << 20;
  const int S = 2048, D = 2048, FF = 8192;

  u16* W_QKV = (u16*)(ws);               // 24 MB
  u16* W_O   = (u16*)(ws + 24 * MB);     // 8 MB
  u16* W_G   = (u16*)(ws + 32 * MB);     // 32 MB
  u16* W_U   = (u16*)(ws + 64 * MB);     // 32 MB
  u16* W_D   = (u16*)(ws + 96 * MB);     // 32 MB
  u16* HB    = (u16*)(ws + 128 * MB);    // 8 MB
  u16* QKVB  = (u16*)(ws + 136 * MB);    // 24 MB (q,k,v)
  u16* VT    = (u16*)(ws + 160 * MB);    // 8 MB
  u16* ATTNB = (u16*)(ws + 168 * MB);    // 8 MB
  float* X1  = (float*)(ws + 176 * MB);  // 16 MB
  u16* H2B   = (u16*)(ws + 192 * MB);    // 8 MB
  float2* RT = (float2*)(ws + 200 * MB); // 0.5 MB
  u16* GATEB = (u16*)(ws);               // 32 MB, overlays W_QKV+W_O (dead after O-proj)
  u16* PRODB = (u16*)(ws + 136 * MB);    // 32 MB, overlays QKVB+VT (dead after attention)
  u16* DP    = (u16*)(ws);               // 32 MB bf16 down-proj partials (overlays GATEB)
  u16* OP    = (u16*)(ws + 208 * MB);    // 32 MB bf16 O-proj partials
  const bool splitO = ws_size >= 240 * MB;

  prep<<<8448, 256, 0, stream>>>(x, w_in, wq, wk, wv, HB, W_QKV, RT);
  gemm8<0><<<dim3(64, 1, 3), 512, 0, stream>>>(HB, W_QKV, QKVB, nullptr, S, D, D, D, D, 0,
                                               (long long)D * D, (long long)S * D);
  rope_tr<<<4096, 256, 0, stream>>>(QKVB, QKVB + (size_t)S * D, RT, QKVB + 2 * (size_t)S * D, VT, wo, W_O);
  attn_cast<<<2048, 256, 0, stream>>>(QKVB, QKVB + (size_t)S * D, VT, ATTNB, wg, wu, wd, W_G, W_U, W_D);
  if (splitO) {
    gemm8<3><<<dim3(64, 1, 4), 512, 0, stream>>>(ATTNB, W_O, OP, nullptr, S, D, 512, D, D, 512, 0, 0);
    reduce_norm<<<S, 256, 0, stream>>>(OP, x, w_pn, X1, H2B);
  } else {
    gemm8<1><<<dim3(64, 1, 1), 512, 0, stream>>>(ATTNB, W_O, X1, x, S, D, D, D, D, 0, 0, 0);
    rmsnorm_cast<<<S, 256, 0, stream>>>(X1, w_pn, H2B);
  }
  gemm8<0><<<dim3(256, 1, 1), 512, 0, stream>>>(H2B, W_G, GATEB, nullptr, S, FF, D, D, D, 0, 0, 0);
  gemm8<2><<<dim3(256, 1, 1), 512, 0, stream>>>(H2B, W_U, PRODB, GATEB, S, FF, D, D, D, 0, 0, 0);
  gemm8<3><<<dim3(64, 1, 4), 512, 0, stream>>>(PRODB, W_D, DP, nullptr, S, D, 2048, FF, FF, 2048, 0, 0);
  reduce4<<<(S * D) / 2048, 256, 0, stream>>>(DP, X1, out, (size_t)S * D);
  (void)in_sizes; (void)n_in; (void)out_size;
}